// Round 8
// baseline (194.905 us; speedup 1.0000x reference)
//
#include <hip/hip_runtime.h>
#include <math.h>

#define NA   4096
#define DA   128
#define DM   512
#define NT   1024
#define HH   4
#define DF   512
#define PP   32768
#define WIN  16
#define BAND 33
#define KSTR 132   // padded f32 LDS row stride

typedef __attribute__((ext_vector_type(8))) short bf16x8;
typedef __attribute__((ext_vector_type(4))) float f32x4;

__device__ __forceinline__ float sigmoidf_(float x) { return 1.0f / (1.0f + __expf(-x)); }
__device__ __forceinline__ ushort f2bf(float f) {
    union { float f; unsigned int i; } x; x.f = f;
    unsigned int r = x.i + 0x7fffu + ((x.i >> 16) & 1u);
    return (ushort)(r >> 16);
}

#define MFMA(a, b, c) __builtin_amdgcn_mfma_f32_16x16x32_bf16((a), (b), (c), 0, 0, 0)

// ---------------------------------------------------------------------------
// Prep: bf16 weight transposes (32x32 LDS tiles) + activation converts.
// grid (64, 15)
// ---------------------------------------------------------------------------
__global__ __launch_bounds__(256) void k_prep(
    const float* __restrict__ hc, const float* __restrict__ ca,
    const float* __restrict__ cw, const float* __restrict__ a1, const float* __restrict__ a2,
    const float* __restrict__ wq, const float* __restrict__ wk, const float* __restrict__ wv,
    const float* __restrict__ wg, const float* __restrict__ wo,
    const float* __restrict__ g1, const float* __restrict__ g2,
    const float* __restrict__ s1, const float* __restrict__ s3, const float* __restrict__ s2,
    ushort* hcb, ushort* cab, ushort* cwT, ushort* a1T, ushort* a2T,
    ushort* wqT, ushort* wkT, ushort* wvT, ushort* wgT, ushort* woT,
    ushort* g1T, ushort* g2T, ushort* s1T, ushort* s3T, ushort* s2T)
{
    __shared__ float tile[32][33];
    const int y = blockIdx.y, bx = blockIdx.x, tid = threadIdx.x;
    if (y <= 1) {
        const float4* src = (const float4*)(y == 0 ? hc : ca);
        ushort* dst = y == 0 ? hcb : cab;
        for (int i = bx * 256 + tid; i < 131072; i += 16384) {
            float4 v = src[i];
            ushort4 st; st.x = f2bf(v.x); st.y = f2bf(v.y); st.z = f2bf(v.z); st.w = f2bf(v.w);
            *(ushort4*)&dst[(size_t)i * 4] = st;
        }
        return;
    }
    const float* src; ushort* dst; int K, N;
    switch (y) {
        case 2:  src = cw; dst = cwT; K = 512; N = 128; break;
        case 3:  src = a1; dst = a1T; K = 128; N = 256; break;
        case 4:  src = a2; dst = a2T; K = 128; N = 256; break;
        case 5:  src = wq; dst = wqT; K = 128; N = 128; break;
        case 6:  src = wk; dst = wkT; K = 128; N = 128; break;
        case 7:  src = wv; dst = wvT; K = 128; N = 128; break;
        case 8:  src = wg; dst = wgT; K = 128; N = 128; break;
        case 9:  src = wo; dst = woT; K = 128; N = 128; break;
        case 10: src = g1; dst = g1T; K = 128; N = 128; break;
        case 11: src = g2; dst = g2T; K = 128; N = 128; break;
        case 12: src = s1; dst = s1T; K = 128; N = 512; break;
        case 13: src = s3; dst = s3T; K = 128; N = 512; break;
        default: src = s2; dst = s2T; K = 512; N = 128; break;
    }
    const int tn_cnt = N >> 5;
    if (bx >= (K >> 5) * tn_cnt) return;
    const int k0 = (bx / tn_cnt) << 5, n0 = (bx % tn_cnt) << 5;
    {
        int r = tid >> 3, c = (tid & 7) << 2;
        float4 v = *(const float4*)&src[(size_t)(k0 + r) * N + n0 + c];
        tile[r][c + 0] = v.x; tile[r][c + 1] = v.y;
        tile[r][c + 2] = v.z; tile[r][c + 3] = v.w;
    }
    __syncthreads();
    {
        int rn = tid >> 3, ck = (tid & 7) << 2;
        ushort4 st;
        st.x = f2bf(tile[ck + 0][rn]);
        st.y = f2bf(tile[ck + 1][rn]);
        st.z = f2bf(tile[ck + 2][rn]);
        st.w = f2bf(tile[ck + 3][rn]);
        *(ushort4*)&dst[(size_t)(n0 + rn) * K + k0 + ck] = st;
    }
}

// ---------------------------------------------------------------------------
// Mega kernel: full chain per 16-row block (48-row halo recompute).
// band scatter in LDS; cond/modulators/gates computed in-block.
// grid 256, 512 thr (8 waves), ~144 KB LDS.
// ---------------------------------------------------------------------------
__global__ __launch_bounds__(512) void k_mega(
    const float* __restrict__ qg, const ushort* __restrict__ hcb,
    const ushort* __restrict__ cab, const int* __restrict__ tok,
    const float* __restrict__ t_emb, const float* __restrict__ cond_b,
    const float* __restrict__ ad1b, const float* __restrict__ ad2b,
    const float* __restrict__ g1b, const float* __restrict__ g2b,
    const float* __restrict__ ln_g, const float* __restrict__ ln_b,
    const float* __restrict__ p_lm, const float* __restrict__ pair_w,
    const float* __restrict__ pair_b, const int* __restrict__ p_idx,
    const ushort* __restrict__ cwT, const ushort* __restrict__ a1T,
    const ushort* __restrict__ a2T, const ushort* __restrict__ g1T,
    const ushort* __restrict__ g2T,
    const ushort* __restrict__ wqT, const ushort* __restrict__ wkT,
    const ushort* __restrict__ wvT, const ushort* __restrict__ wgT,
    const ushort* __restrict__ woT, const ushort* __restrict__ s1T,
    const ushort* __restrict__ s3T, const ushort* __restrict__ s2T,
    float* __restrict__ out)
{
    // ---- LDS pool (manual layout; X region is cond_s | att_s | hb_s) ----
    __shared__ __align__(16) char pool[147328];
    float*  K_s     = (float*)(pool + 0);        // 48*132 f32
    float*  V_s     = (float*)(pool + 25344);    // 48*132 f32
    char*   qn_c    = pool + 50688;              // 48*128 bf16 swz
    float*  Q_s     = (float*)(pool + 62976);    // 16*132 f32
    float*  sG_s    = (float*)(pool + 71424);
    float*  q1_s    = (float*)(pool + 79872);
    float*  gate1_s = (float*)(pool + 88320);
    float*  gate2_s = (float*)(pool + 96768);
    float*  g2g_s   = (float*)(pool + 105216);
    float*  g2b_s   = (float*)(pool + 113664);
    float*  mu_s    = (float*)(pool + 122112);   // 48
    float*  rs_s    = (float*)(pool + 122304);   // 48
    char*   cond_c  = pool + 122496;             // 48*128 bf16 swz (dead after A1)
    char*   att_c   = pool + 122496;             // 16*128 bf16 swz (C..D)
    char*   hb_c    = pool + 122496;             // 16*512 bf16 swz (F)
    float*  band_s  = (float*)(pool + 138880);   // 16*4*33 f32

    const int tid = threadIdx.x;
    const int l = tid & 63, wv = tid >> 6;
    const int cl = l & 15, kq = l >> 4, ko = kq * 8;
    const int r0 = blockIdx.x * 16;
    const int hb0 = r0 - 16;

    // ---- band zero ----
    for (int i = tid; i < 16 * HH * BAND; i += 512) band_s[i] = 0.f;
    __syncthreads();

    // ---- band scatter: scan all pairs, keep hits for our 16 rows ----
    for (int p = tid; p < PP; p += 512) {
        int2 ij = *(const int2*)&p_idx[2 * p];
        int ri = ij.x - r0;
        int d = ij.y - ij.x + WIN;
        if (ri < 0 || ri >= 16 || d < 0 || d > 2 * WIN) continue;
        float v0 = pair_b[0], v1 = pair_b[1], v2 = pair_b[2], v3 = pair_b[3];
        #pragma unroll
        for (int k = 0; k < 16; ++k) {
            float a = p_lm[p * 16 + k];
            v0 = fmaf(a, pair_w[k * 4 + 0], v0);
            v1 = fmaf(a, pair_w[k * 4 + 1], v1);
            v2 = fmaf(a, pair_w[k * 4 + 2], v2);
            v3 = fmaf(a, pair_w[k * 4 + 3], v3);
        }
        band_s[ri * 132 + 0 * BAND + d] = v0;
        band_s[ri * 132 + 1 * BAND + d] = v1;
        band_s[ri * 132 + 2 * BAND + d] = v2;
        band_s[ri * 132 + 3 * BAND + d] = v3;
    }

    // ---- Phase A0: cond (waves 0-5) | gates (wave 6) | LN1 stats (wave 7) ----
    if (wv < 6) {
        const int t = wv >> 1, ch = wv & 1;
        int gr = hb0 + t * 16 + cl;
        int grc = gr < 0 ? 0 : (gr >= NA ? NA - 1 : gr);
        const ushort* Arow = hcb + (size_t)tok[grc] * DM;
        const int n0 = ch * 64;
        const ushort* Wc = cwT + (size_t)(n0 + cl) * DM;
        f32x4 acc[4] = {};
        #pragma unroll
        for (int ks = 0; ks < 16; ++ks) {
            bf16x8 a = *(const bf16x8*)(Arow + ks * 32 + ko);
            #pragma unroll
            for (int nf = 0; nf < 4; ++nf) {
                bf16x8 b = *(const bf16x8*)(Wc + (size_t)nf * 16 * DM + ks * 32 + ko);
                acc[nf] = MFMA(a, b, acc[nf]);
            }
        }
        #pragma unroll
        for (int nf = 0; nf < 4; ++nf) {
            int col = n0 + nf * 16 + cl;
            float add = t_emb[col] + cond_b[col];
            #pragma unroll
            for (int r = 0; r < 4; ++r) {
                int row = t * 16 + kq * 4 + r;
                int byte = row * 256 + col * 2;
                byte ^= (row & 7) << 4;
                *(ushort*)(cond_c + byte) = f2bf(acc[nf][r] + add);
            }
        }
    } else if (wv == 6) {
        const ushort* Arow = cab + (size_t)(r0 + cl) * DA;
        f32x4 acc1[8] = {}, acc2[8] = {};
        #pragma unroll
        for (int ks = 0; ks < 4; ++ks) {
            bf16x8 a = *(const bf16x8*)(Arow + ks * 32 + ko);
            #pragma unroll
            for (int nf = 0; nf < 8; ++nf) {
                bf16x8 b1 = *(const bf16x8*)(g1T + (size_t)(nf * 16 + cl) * DA + ks * 32 + ko);
                acc1[nf] = MFMA(a, b1, acc1[nf]);
                bf16x8 b2 = *(const bf16x8*)(g2T + (size_t)(nf * 16 + cl) * DA + ks * 32 + ko);
                acc2[nf] = MFMA(a, b2, acc2[nf]);
            }
        }
        #pragma unroll
        for (int nf = 0; nf < 8; ++nf) {
            int col = nf * 16 + cl;
            #pragma unroll
            for (int r = 0; r < 4; ++r) {
                int row = kq * 4 + r;
                gate1_s[row * KSTR + col] = sigmoidf_(acc1[nf][r] + g1b[col]);
                gate2_s[row * KSTR + col] = sigmoidf_(acc2[nf][r] + g2b[col]);
            }
        }
    } else {
        // wave 7: LN1 stats for 48 halo rows
        #pragma unroll
        for (int rr = 0; rr < 12; ++rr) {
            int hr = rr * 4 + kq;
            int gr = hb0 + hr;
            int grc = gr < 0 ? 0 : (gr >= NA ? NA - 1 : gr);
            float4 v0 = *(const float4*)&qg[(size_t)grc * DA + cl * 8];
            float4 v1 = *(const float4*)&qg[(size_t)grc * DA + cl * 8 + 4];
            float sum = v0.x + v0.y + v0.z + v0.w + v1.x + v1.y + v1.z + v1.w;
            float sq = v0.x * v0.x + v0.y * v0.y + v0.z * v0.z + v0.w * v0.w
                     + v1.x * v1.x + v1.y * v1.y + v1.z * v1.z + v1.w * v1.w;
            sum += __shfl_xor(sum, 1); sq += __shfl_xor(sq, 1);
            sum += __shfl_xor(sum, 2); sq += __shfl_xor(sq, 2);
            sum += __shfl_xor(sum, 4); sq += __shfl_xor(sq, 4);
            sum += __shfl_xor(sum, 8); sq += __shfl_xor(sq, 8);
            if (cl == 0) {
                float m = sum * (1.0f / DA);
                mu_s[hr] = m;
                rs_s[hr] = rsqrtf(sq * (1.0f / DA) - m * m + 1e-5f);
            }
        }
    }
    __syncthreads();

    // ---- Phase A1: LN1+modulate->qn (waves 0-5) | gb2 (waves 6,7) ----
    if (wv < 6) {
        const int t = wv >> 1, ch = wv & 1;
        const int n0 = ch * 64;
        f32x4 gacc[4] = {}, bacc[4] = {};
        #pragma unroll
        for (int ks = 0; ks < 4; ++ks) {
            int byteA = (t * 16 + cl) * 256 + (ks * 32 + ko) * 2;
            byteA ^= (cl & 7) << 4;
            bf16x8 a = *(const bf16x8*)(cond_c + byteA);
            #pragma unroll
            for (int nf = 0; nf < 4; ++nf) {
                bf16x8 bg = *(const bf16x8*)(a1T + (size_t)(n0 + nf * 16 + cl) * DA + ks * 32 + ko);
                gacc[nf] = MFMA(a, bg, gacc[nf]);
                bf16x8 bb = *(const bf16x8*)(a1T + (size_t)(128 + n0 + nf * 16 + cl) * DA + ks * 32 + ko);
                bacc[nf] = MFMA(a, bb, bacc[nf]);
            }
        }
        #pragma unroll
        for (int nf = 0; nf < 4; ++nf) {
            int col = n0 + nf * 16 + cl;
            float lg = ln_g[col], lb = ln_b[col];
            float b1v = ad1b[col], b2v = ad1b[128 + col];
            #pragma unroll
            for (int r = 0; r < 4; ++r) {
                int row = t * 16 + kq * 4 + r;
                int gr = hb0 + row;
                int grc = gr < 0 ? 0 : (gr >= NA ? NA - 1 : gr);
                float g = gacc[nf][r] + b1v;
                float b = bacc[nf][r] + b2v;
                float qv = qg[(size_t)grc * DA + col];
                float xn = (qv - mu_s[row]) * rs_s[row] * lg + lb;
                int byte = row * 256 + col * 2;
                byte ^= (row & 7) << 4;
                *(ushort*)(qn_c + byte) = f2bf((1.f + g) * xn + b);
            }
        }
    } else {
        const int off = (wv == 7) ? 128 : 0;
        float* dst = (wv == 7) ? g2b_s : g2g_s;
        f32x4 acc[8] = {};
        #pragma unroll
        for (int ks = 0; ks < 4; ++ks) {
            int byteA = (16 + cl) * 256 + (ks * 32 + ko) * 2;
            byteA ^= (cl & 7) << 4;
            bf16x8 a = *(const bf16x8*)(cond_c + byteA);
            #pragma unroll
            for (int nf = 0; nf < 8; ++nf) {
                bf16x8 b = *(const bf16x8*)(a2T + (size_t)(off + nf * 16 + cl) * DA + ks * 32 + ko);
                acc[nf] = MFMA(a, b, acc[nf]);
            }
        }
        #pragma unroll
        for (int nf = 0; nf < 8; ++nf) {
            int col = nf * 16 + cl;
            float bb = ad2b[off + col];
            #pragma unroll
            for (int r = 0; r < 4; ++r)
                dst[(kq * 4 + r) * KSTR + col] = acc[nf][r] + bb;
        }
    }
    __syncthreads();

    // ---- Phase B: QKVG MFMA. waves 0-5: (tile, K/V); 6: Q t1; 7: G t1 ----
    {
        int t, isV = 0;
        const ushort* WT;
        if (wv < 6) { t = wv >> 1; isV = wv & 1; WT = isV ? wvT : wkT; }
        else        { t = 1; WT = (wv == 6) ? wqT : wgT; }
        const ushort* Wc = WT + (size_t)cl * DA;
        f32x4 acc[8] = {};
        #pragma unroll
        for (int ks = 0; ks < 4; ++ks) {
            int byteA = (t * 16 + cl) * 256 + (ks * 32 + ko) * 2;
            byteA ^= (cl & 7) << 4;
            bf16x8 a = *(const bf16x8*)(qn_c + byteA);
            #pragma unroll
            for (int nf = 0; nf < 8; ++nf) {
                bf16x8 b = *(const bf16x8*)(Wc + (size_t)nf * 16 * DA + ks * 32 + ko);
                acc[nf] = MFMA(a, b, acc[nf]);
            }
        }
        if (wv < 6) {
            float* dst = isV ? V_s : K_s;
            #pragma unroll
            for (int nf = 0; nf < 8; ++nf)
                #pragma unroll
                for (int r = 0; r < 4; ++r)
                    dst[(t * 16 + kq * 4 + r) * KSTR + nf * 16 + cl] = acc[nf][r];
        } else if (wv == 6) {
            #pragma unroll
            for (int nf = 0; nf < 8; ++nf)
                #pragma unroll
                for (int r = 0; r < 4; ++r)
                    Q_s[(kq * 4 + r) * KSTR + nf * 16 + cl] = acc[nf][r];
        } else {
            #pragma unroll
            for (int nf = 0; nf < 8; ++nf)
                #pragma unroll
                for (int r = 0; r < 4; ++r)
                    sG_s[(kq * 4 + r) * KSTR + nf * 16 + cl] = sigmoidf_(acc[nf][r]);
        }
    }
    __syncthreads();

    // ---- Phase C: banded attention (f32, LDS) -> att_c ----
    {
        const int g = tid >> 3, l3 = tid & 7;
        const int rl = g >> 2, h = g & 3;
        const int gr = r0 + rl;
        const float scale = 0.17677669529663687f;   // 1/sqrt(32)
        float4 qr0 = *(const float4*)&Q_s[rl * KSTR + h * 32 + l3 * 4];
        const float* brow = band_s + rl * 132 + h * BAND;
        float s[BAND];
        float m = -1e30f;
        #pragma unroll
        for (int jo = 0; jo < BAND; ++jo) {
            int j = gr - WIN + jo;
            float sv = -1e30f;
            if ((unsigned)j < NA) {
                float4 kk = *(const float4*)&K_s[(rl + jo) * KSTR + h * 32 + l3 * 4];
                float d = 0.f;
                d = fmaf(qr0.x, kk.x, d); d = fmaf(qr0.y, kk.y, d);
                d = fmaf(qr0.z, kk.z, d); d = fmaf(qr0.w, kk.w, d);
                d += __shfl_xor(d, 1);
                d += __shfl_xor(d, 2);
                d += __shfl_xor(d, 4);
                sv = fmaf(d, scale, brow[jo]);
            }
            s[jo] = sv;
            m = fmaxf(m, sv);
        }
        float lsum = 0.f;
        #pragma unroll
        for (int jo = 0; jo < BAND; ++jo) {
            float p = __expf(s[jo] - m);
            s[jo] = p;
            lsum += p;
        }
        float inv = 1.0f / lsum;
        float4 o = {0.f, 0.f, 0.f, 0.f};
        #pragma unroll
        for (int jo = 0; jo < BAND; ++jo) {
            int j = gr - WIN + jo;
            if ((unsigned)j < NA) {
                float4 v = *(const float4*)&V_s[(rl + jo) * KSTR + h * 32 + l3 * 4];
                o.x = fmaf(s[jo], v.x, o.x);
                o.y = fmaf(s[jo], v.y, o.y);
                o.z = fmaf(s[jo], v.z, o.z);
                o.w = fmaf(s[jo], v.w, o.w);
            }
        }
        ushort4 st;
        st.x = f2bf(o.x * inv); st.y = f2bf(o.y * inv);
        st.z = f2bf(o.z * inv); st.w = f2bf(o.w * inv);
        int byte = rl * 256 + h * 64 + l3 * 8;
        byte ^= (rl & 7) << 4;
        *(ushort4*)(att_c + byte) = st;
    }
    __syncthreads();

    // ---- Phase D: wo MFMA + gated residual -> q1_s ----
    {
        const int n0 = wv * 16;
        const ushort* Wc = woT + (size_t)(n0 + cl) * DA;
        f32x4 acc = {0.f, 0.f, 0.f, 0.f};
        #pragma unroll
        for (int ks = 0; ks < 4; ++ks) {
            int byteA = cl * 256 + (ks * 32 + ko) * 2;
            byteA ^= (cl & 7) << 4;
            bf16x8 a = *(const bf16x8*)(att_c + byteA);
            bf16x8 b = *(const bf16x8*)(Wc + ks * 32 + ko);
            acc = MFMA(a, b, acc);
        }
        #pragma unroll
        for (int r = 0; r < 4; ++r) {
            int row = kq * 4 + r;
            int gr = r0 + row, col = n0 + cl;
            float qv = qg[(size_t)gr * DA + col];
            float sg = sG_s[row * KSTR + col];
            float g1v = gate1_s[row * KSTR + col];
            q1_s[row * KSTR + col] = (qv + sg * acc[r]) * (1.f + g1v);
        }
    }
    __syncthreads();

    // ---- Phase E: LN2 + gb2 modulate (in-reg, lane cl owns row cl) ----
    bf16x8 afr[4];
    {
        const int row = cl;
        float qv2[4][8];
        float sum = 0.f, sq = 0.f;
        #pragma unroll
        for (int ks = 0; ks < 4; ++ks) {
            float4 v0 = *(const float4*)&q1_s[row * KSTR + ks * 32 + ko];
            float4 v1 = *(const float4*)&q1_s[row * KSTR + ks * 32 + ko + 4];
            qv2[ks][0] = v0.x; qv2[ks][1] = v0.y; qv2[ks][2] = v0.z; qv2[ks][3] = v0.w;
            qv2[ks][4] = v1.x; qv2[ks][5] = v1.y; qv2[ks][6] = v1.z; qv2[ks][7] = v1.w;
            sum += v0.x + v0.y + v0.z + v0.w + v1.x + v1.y + v1.z + v1.w;
            sq += v0.x * v0.x + v0.y * v0.y + v0.z * v0.z + v0.w * v0.w
                + v1.x * v1.x + v1.y * v1.y + v1.z * v1.z + v1.w * v1.w;
        }
        sum += __shfl_xor(sum, 16); sq += __shfl_xor(sq, 16);
        sum += __shfl_xor(sum, 32); sq += __shfl_xor(sq, 32);
        float mean = sum * (1.0f / DA);
        float rs = rsqrtf(sq * (1.0f / DA) - mean * mean + 1e-5f);
        #pragma unroll
        for (int ks = 0; ks < 4; ++ks) {
            int k = ks * 32 + ko;
            float4 g0 = *(const float4*)&g2g_s[row * KSTR + k];
            float4 g1v = *(const float4*)&g2g_s[row * KSTR + k + 4];
            float4 b0 = *(const float4*)&g2b_s[row * KSTR + k];
            float4 b1v = *(const float4*)&g2b_s[row * KSTR + k + 4];
            float gg[8] = {g0.x, g0.y, g0.z, g0.w, g1v.x, g1v.y, g1v.z, g1v.w};
            float bb[8] = {b0.x, b0.y, b0.z, b0.w, b1v.x, b1v.y, b1v.z, b1v.w};
            #pragma unroll
            for (int j = 0; j < 8; ++j) {
                float xn = (qv2[ks][j] - mean) * rs;
                afr[ks][j] = (short)f2bf((1.f + gg[j]) * xn + bb[j]);
            }
        }
    }

    // ---- Phase F: sw1/sw3 -> hb_c; sw2 -> out ----
    {
        const int c0 = wv * 64;
        const ushort* W1 = s1T + (size_t)(c0 + cl) * DA;
        const ushort* W3 = s3T + (size_t)(c0 + cl) * DA;
        f32x4 acc1[4] = {}, acc3[4] = {};
        #pragma unroll
        for (int ks = 0; ks < 4; ++ks) {
            #pragma unroll
            for (int nf = 0; nf < 4; ++nf) {
                bf16x8 b1 = *(const bf16x8*)(W1 + (size_t)nf * 16 * DA + ks * 32 + ko);
                acc1[nf] = MFMA(afr[ks], b1, acc1[nf]);
                bf16x8 b3 = *(const bf16x8*)(W3 + (size_t)nf * 16 * DA + ks * 32 + ko);
                acc3[nf] = MFMA(afr[ks], b3, acc3[nf]);
            }
        }
        __syncthreads();   // att_c dead; hb_c aliases it
        #pragma unroll
        for (int nf = 0; nf < 4; ++nf) {
            #pragma unroll
            for (int r = 0; r < 4; ++r) {
                float x1 = acc1[nf][r], x3 = acc3[nf][r];
                float h = x1 * sigmoidf_(x1) * x3;
                int rr = kq * 4 + r;
                int col = c0 + nf * 16 + cl;
                int byte = rr * 1024 + col * 2;
                byte ^= (rr & 7) << 4;
                *(ushort*)(hb_c + byte) = f2bf(h);
            }
        }
    }
    __syncthreads();
    {
        const int n0 = wv * 16;
        const ushort* W2 = s2T + (size_t)(n0 + cl) * DF;
        f32x4 acc = {0.f, 0.f, 0.f, 0.f};
        #pragma unroll
        for (int ks = 0; ks < 16; ++ks) {
            int byteA = cl * 1024 + (ks * 32 + ko) * 2;
            byteA ^= (cl & 7) << 4;
            bf16x8 a = *(const bf16x8*)(hb_c + byteA);
            bf16x8 b = *(const bf16x8*)(W2 + ks * 32 + ko);
            acc = MFMA(a, b, acc);
        }
        #pragma unroll
        for (int r = 0; r < 4; ++r) {
            int row = kq * 4 + r;
            int gr = r0 + row, col = n0 + cl;
            size_t rc = (size_t)gr * DA + col;
            out[rc] = q1_s[row * KSTR + col] + gate2_s[row * KSTR + col] * acc[r];
        }
    }
}

// ---------------------------------------------------------------------------
extern "C" void kernel_launch(void* const* d_in, const int* in_sizes, int n_in,
                              void* d_out, int out_size, void* d_ws, size_t ws_size,
                              hipStream_t stream)
{
    const float* q      = (const float*)d_in[0];
    const float* c_atom = (const float*)d_in[1];
    const float* h_cond = (const float*)d_in[2];
    const float* p_lm   = (const float*)d_in[3];
    const float* t_emb  = (const float*)d_in[4];
    const float* cond_w = (const float*)d_in[5];
    const float* cond_b = (const float*)d_in[6];
    const float* ad1w   = (const float*)d_in[7];
    const float* ad1b   = (const float*)d_in[8];
    const float* ad2w   = (const float*)d_in[9];
    const float* ad2b   = (const float*)d_in[10];
    const float* ln_g   = (const float*)d_in[11];
    const float* ln_b   = (const float*)d_in[12];
    const float* wq     = (const float*)d_in[13];
    const float* wk     = (const float*)d_in[14];
    const float* wv     = (const float*)d_in[15];
    const float* wg     = (const float*)d_in[16];
    const float* wo     = (const float*)d_in[17];
    const float* pair_w = (const float*)d_in[18];
    const float* pair_b = (const float*)d_in[19];
    const float* g1w    = (const float*)d_in[20];
    const float* g1b    = (const float*)d_in[21];
    const float* g2w    = (const float*)d_in[22];
    const float* g2b    = (const float*)d_in[23];
    const float* sw1    = (const float*)d_in[24];
    const float* sw3    = (const float*)d_in[25];
    const float* sw2    = (const float*)d_in[26];
    const int*   p_idx  = (const int*)d_in[27];
    const int*   tok    = (const int*)d_in[28];
    float* out = (float*)d_out;

    size_t off = 0;
    char* base = (char*)d_ws;
    auto alloc = [&](size_t bytes) -> void* {
        void* p = base + off;
        off += (bytes + 255) & ~(size_t)255;
        return p;
    };
    ushort* hcb = (ushort*)alloc((size_t)NT * DM * 2);
    ushort* cab = (ushort*)alloc((size_t)NA * DA * 2);
    ushort* cwT = (ushort*)alloc((size_t)DM * DA * 2);
    ushort* a1T = (ushort*)alloc((size_t)256 * 128 * 2);
    ushort* a2T = (ushort*)alloc((size_t)256 * 128 * 2);
    ushort* wqT = (ushort*)alloc((size_t)128 * 128 * 2);
    ushort* wkT = (ushort*)alloc((size_t)128 * 128 * 2);
    ushort* wvT = (ushort*)alloc((size_t)128 * 128 * 2);
    ushort* wgT = (ushort*)alloc((size_t)128 * 128 * 2);
    ushort* woT = (ushort*)alloc((size_t)128 * 128 * 2);
    ushort* g1T = (ushort*)alloc((size_t)128 * 128 * 2);
    ushort* g2T = (ushort*)alloc((size_t)128 * 128 * 2);
    ushort* s1T = (ushort*)alloc((size_t)512 * 128 * 2);
    ushort* s3T = (ushort*)alloc((size_t)512 * 128 * 2);
    ushort* s2T = (ushort*)alloc((size_t)128 * 512 * 2);

    k_prep<<<dim3(64, 15), 256, 0, stream>>>(
        h_cond, c_atom, cond_w, ad1w, ad2w, wq, wk, wv, wg, wo,
        g1w, g2w, sw1, sw3, sw2,
        hcb, cab, cwT, a1T, a2T, wqT, wkT, wvT, wgT, woT,
        g1T, g2T, s1T, s3T, s2T);
    k_mega<<<256, 512, 0, stream>>>(
        q, hcb, cab, tok, t_emb, cond_b, ad1b, ad2b, g1b, g2b,
        ln_g, ln_b, p_lm, pair_w, pair_b, p_idx,
        cwT, a1T, a2T, g1T, g2T,
        wqT, wkT, wvT, wgT, woT, s1T, s3T, s2T, out);
    (void)in_sizes; (void)n_in; (void)out_size; (void)ws_size;
}

// Round 9
// 168.138 us; speedup vs baseline: 1.1592x; 1.1592x over previous
//
#include <hip/hip_runtime.h>
#include <math.h>

#define NA   4096
#define DA   128
#define DM   512
#define NT   1024
#define HH   4
#define DF   512
#define PP   32768
#define WIN  16
#define BAND 33

typedef __attribute__((ext_vector_type(8))) short bf16x8;
typedef __attribute__((ext_vector_type(4))) float f32x4;

__device__ __forceinline__ float sigmoidf_(float x) { return 1.0f / (1.0f + __expf(-x)); }
__device__ __forceinline__ ushort f2bf(float f) {
    union { float f; unsigned int i; } x; x.f = f;
    unsigned int r = x.i + 0x7fffu + ((x.i >> 16) & 1u);
    return (ushort)(r >> 16);
}
__device__ __forceinline__ float bf2f(ushort u) {
    union { unsigned int i; float f; } x; x.i = ((unsigned int)u) << 16;
    return x.f;
}

#define MFMA(a, b, c) __builtin_amdgcn_mfma_f32_16x16x32_bf16((a), (b), (c), 0, 0, 0)

// ---------------------------------------------------------------------------
// Prep: bf16 weight transposes (32x32 LDS tiles) + band zero.  grid (64, 14)
// ---------------------------------------------------------------------------
__global__ __launch_bounds__(256) void k_prep(
    const float* __restrict__ cw, const float* __restrict__ a1, const float* __restrict__ a2,
    const float* __restrict__ wq, const float* __restrict__ wk, const float* __restrict__ wv,
    const float* __restrict__ wg, const float* __restrict__ wo,
    const float* __restrict__ g1, const float* __restrict__ g2,
    const float* __restrict__ s1, const float* __restrict__ s3, const float* __restrict__ s2,
    ushort* cwT, ushort* a1T, ushort* a2T,
    ushort* wqT, ushort* wkT, ushort* wvT, ushort* wgT, ushort* woT,
    ushort* g1T, ushort* g2T, ushort* s1T, ushort* s3T, ushort* s2T,
    float* band)
{
    __shared__ float tile[32][33];
    const int y = blockIdx.y, bx = blockIdx.x, tid = threadIdx.x;
    if (y == 13) {
        float4 z = {0.f, 0.f, 0.f, 0.f};
        float4* b4 = (float4*)band;
        for (int i = bx * 256 + tid; i < 135168; i += 16384) b4[i] = z;
        return;
    }
    const float* src; ushort* dst; int K, N;
    switch (y) {
        case 0:  src = cw; dst = cwT; K = 512; N = 128; break;
        case 1:  src = a1; dst = a1T; K = 128; N = 256; break;
        case 2:  src = a2; dst = a2T; K = 128; N = 256; break;
        case 3:  src = wq; dst = wqT; K = 128; N = 128; break;
        case 4:  src = wk; dst = wkT; K = 128; N = 128; break;
        case 5:  src = wv; dst = wvT; K = 128; N = 128; break;
        case 6:  src = wg; dst = wgT; K = 128; N = 128; break;
        case 7:  src = wo; dst = woT; K = 128; N = 128; break;
        case 8:  src = g1; dst = g1T; K = 128; N = 128; break;
        case 9:  src = g2; dst = g2T; K = 128; N = 128; break;
        case 10: src = s1; dst = s1T; K = 128; N = 512; break;
        case 11: src = s3; dst = s3T; K = 128; N = 512; break;
        default: src = s2; dst = s2T; K = 512; N = 128; break;
    }
    const int tn_cnt = N >> 5;
    if (bx >= (K >> 5) * tn_cnt) return;
    const int k0 = (bx / tn_cnt) << 5, n0 = (bx % tn_cnt) << 5;
    {
        int r = tid >> 3, c = (tid & 7) << 2;
        float4 v = *(const float4*)&src[(size_t)(k0 + r) * N + n0 + c];
        tile[r][c + 0] = v.x; tile[r][c + 1] = v.y;
        tile[r][c + 2] = v.z; tile[r][c + 3] = v.w;
    }
    __syncthreads();
    {
        int rn = tid >> 3, ck = (tid & 7) << 2;
        ushort4 st;
        st.x = f2bf(tile[ck + 0][rn]);
        st.y = f2bf(tile[ck + 1][rn]);
        st.z = f2bf(tile[ck + 2][rn]);
        st.w = f2bf(tile[ck + 3][rn]);
        *(ushort4*)&dst[(size_t)(n0 + rn) * K + k0 + ck] = st;
    }
}

// ---------------------------------------------------------------------------
// condmod: b<256: cond GEMM (16 rows, f32 gather + in-reg cvt) -> gb1/gb2
// (bf16) + gates (f32).  b>=256: pair-bias scatter.  grid 384, 256 thr.
// ---------------------------------------------------------------------------
__global__ __launch_bounds__(256) void k_condmod(
    const float* __restrict__ h_cond, const int* __restrict__ tok,
    const ushort* __restrict__ cwT, const float* __restrict__ t_emb,
    const float* __restrict__ cond_b, const float* __restrict__ c_atom,
    const ushort* __restrict__ a1T, const ushort* __restrict__ a2T,
    const ushort* __restrict__ g1T, const ushort* __restrict__ g2T,
    const float* __restrict__ ad1b, const float* __restrict__ ad2b,
    const float* __restrict__ g1b, const float* __restrict__ g2b,
    const float* __restrict__ p_lm, const float* __restrict__ pair_w,
    const float* __restrict__ pair_b, const int* __restrict__ p_idx,
    float* __restrict__ band,
    ushort* __restrict__ gb1, ushort* __restrict__ gb2,
    float* __restrict__ gate1, float* __restrict__ gate2)
{
    const int tid = threadIdx.x, b = blockIdx.x;
    if (b >= 256) {
        int p = (b - 256) * 256 + tid;      // 128 x 256 = PP
        int i = p_idx[2 * p], j = p_idx[2 * p + 1];
        int d = j - i + WIN;
        if (d < 0 || d > 2 * WIN) return;
        float v0 = pair_b[0], v1 = pair_b[1], v2 = pair_b[2], v3 = pair_b[3];
        #pragma unroll
        for (int k = 0; k < 16; ++k) {
            float a = p_lm[p * 16 + k];
            v0 = fmaf(a, pair_w[k * 4 + 0], v0);
            v1 = fmaf(a, pair_w[k * 4 + 1], v1);
            v2 = fmaf(a, pair_w[k * 4 + 2], v2);
            v3 = fmaf(a, pair_w[k * 4 + 3], v3);
        }
        size_t base = ((size_t)i * HH) * BAND + d;
        band[base + 0 * BAND] = v0;
        band[base + 1 * BAND] = v1;
        band[base + 2 * BAND] = v2;
        band[base + 3 * BAND] = v3;
        return;
    }
    __shared__ ushort cond_s[16 * 128];   // swizzled bf16
    const int l = tid & 63, wv = tid >> 6;
    const int cl = l & 15, kq = l >> 4, ko = kq * 8;
    const int r0 = b * 16;
    // cond: wave wv -> cols wv*32..+31, K=512 (A = gathered f32, cvt in-reg)
    {
        const float* Arow = h_cond + (size_t)tok[r0 + cl] * DM;
        const int n0 = wv * 32;
        const ushort* Wc = cwT + (size_t)(n0 + cl) * DM;
        f32x4 acc[2] = {};
        #pragma unroll
        for (int ks = 0; ks < 16; ++ks) {
            float4 x0 = *(const float4*)(Arow + ks * 32 + ko);
            float4 x1 = *(const float4*)(Arow + ks * 32 + ko + 4);
            bf16x8 a;
            a[0] = (short)f2bf(x0.x); a[1] = (short)f2bf(x0.y);
            a[2] = (short)f2bf(x0.z); a[3] = (short)f2bf(x0.w);
            a[4] = (short)f2bf(x1.x); a[5] = (short)f2bf(x1.y);
            a[6] = (short)f2bf(x1.z); a[7] = (short)f2bf(x1.w);
            #pragma unroll
            for (int nf = 0; nf < 2; ++nf) {
                bf16x8 bb = *(const bf16x8*)(Wc + (size_t)nf * 16 * DM + ks * 32 + ko);
                acc[nf] = MFMA(a, bb, acc[nf]);
            }
        }
        #pragma unroll
        for (int nf = 0; nf < 2; ++nf) {
            int col = n0 + nf * 16 + cl;
            float add = t_emb[col] + cond_b[col];
            #pragma unroll
            for (int r = 0; r < 4; ++r) {
                int row = kq * 4 + r;
                int byte = row * 256 + col * 2;
                byte ^= (row & 7) << 4;
                *(ushort*)((char*)cond_s + byte) = f2bf(acc[nf][r] + add);
            }
        }
    }
    __syncthreads();
    // gb1/gb2: wave wv -> cols wv*64..+63 of 256 (bf16 out)
    {
        const int n0 = wv * 64;
        const ushort* W1c = a1T + (size_t)(n0 + cl) * DA;
        const ushort* W2c = a2T + (size_t)(n0 + cl) * DA;
        f32x4 acc1[4] = {}, acc2[4] = {};
        #pragma unroll
        for (int ks = 0; ks < 4; ++ks) {
            int byteA = cl * 256 + (ks * 32 + ko) * 2;
            byteA ^= (cl & 7) << 4;
            bf16x8 a = *(const bf16x8*)((char*)cond_s + byteA);
            #pragma unroll
            for (int nf = 0; nf < 4; ++nf) {
                bf16x8 b1 = *(const bf16x8*)(W1c + (size_t)nf * 16 * DA + ks * 32 + ko);
                acc1[nf] = MFMA(a, b1, acc1[nf]);
                bf16x8 b2 = *(const bf16x8*)(W2c + (size_t)nf * 16 * DA + ks * 32 + ko);
                acc2[nf] = MFMA(a, b2, acc2[nf]);
            }
        }
        #pragma unroll
        for (int nf = 0; nf < 4; ++nf) {
            int col = n0 + nf * 16 + cl;
            float b1v = ad1b[col], b2v = ad2b[col];
            #pragma unroll
            for (int r = 0; r < 4; ++r) {
                size_t rc = (size_t)(r0 + kq * 4 + r) * 256 + col;
                gb1[rc] = f2bf(acc1[nf][r] + b1v);
                gb2[rc] = f2bf(acc2[nf][r] + b2v);
            }
        }
    }
    // gates: wave wv -> cols wv*32..+31 (A = c_atom f32, cvt in-reg)
    {
        const float* Arow = c_atom + (size_t)(r0 + cl) * DA;
        const int n0 = wv * 32;
        const ushort* W1c = g1T + (size_t)(n0 + cl) * DA;
        const ushort* W2c = g2T + (size_t)(n0 + cl) * DA;
        f32x4 acc1[2] = {}, acc2[2] = {};
        #pragma unroll
        for (int ks = 0; ks < 4; ++ks) {
            float4 x0 = *(const float4*)(Arow + ks * 32 + ko);
            float4 x1 = *(const float4*)(Arow + ks * 32 + ko + 4);
            bf16x8 a;
            a[0] = (short)f2bf(x0.x); a[1] = (short)f2bf(x0.y);
            a[2] = (short)f2bf(x0.z); a[3] = (short)f2bf(x0.w);
            a[4] = (short)f2bf(x1.x); a[5] = (short)f2bf(x1.y);
            a[6] = (short)f2bf(x1.z); a[7] = (short)f2bf(x1.w);
            #pragma unroll
            for (int nf = 0; nf < 2; ++nf) {
                bf16x8 b1 = *(const bf16x8*)(W1c + (size_t)nf * 16 * DA + ks * 32 + ko);
                acc1[nf] = MFMA(a, b1, acc1[nf]);
                bf16x8 b2 = *(const bf16x8*)(W2c + (size_t)nf * 16 * DA + ks * 32 + ko);
                acc2[nf] = MFMA(a, b2, acc2[nf]);
            }
        }
        #pragma unroll
        for (int nf = 0; nf < 2; ++nf) {
            int col = n0 + nf * 16 + cl;
            float b1v = g1b[col], b2v = g2b[col];
            #pragma unroll
            for (int r = 0; r < 4; ++r) {
                size_t rc = (size_t)(r0 + kq * 4 + r) * DA + col;
                gate1[rc] = sigmoidf_(acc1[nf][r] + b1v);
                gate2[rc] = sigmoidf_(acc2[nf][r] + b2v);
            }
        }
    }
}

// ---------------------------------------------------------------------------
// Mega: per 16-row block, stage ALL cold data first, then
// LN1 -> QKVG -> attn -> wo -> LN2 -> FFN from LDS.  grid 256, 512 thr.
// ---------------------------------------------------------------------------
__global__ __launch_bounds__(512) void k_mega(
    const float* __restrict__ qg, const ushort* __restrict__ gb1g,
    const ushort* __restrict__ gb2g, const float* __restrict__ gate1g,
    const float* __restrict__ gate2g, const float* __restrict__ ln_g,
    const float* __restrict__ ln_b, const float* __restrict__ bandg,
    const ushort* __restrict__ wqT, const ushort* __restrict__ wkT,
    const ushort* __restrict__ wvT, const ushort* __restrict__ wgT,
    const ushort* __restrict__ woT, const ushort* __restrict__ s1T,
    const ushort* __restrict__ s3T, const ushort* __restrict__ s2T,
    float* __restrict__ out)
{
    __shared__ __align__(16) char pool[162944];
    float*  q_s     = (float*)(pool + 0);        // 48*132 f32 staged q
    ushort* gb1_s   = (ushort*)(pool + 25344);   // 48*260 bf16
    ushort* gb2_s   = (ushort*)(pool + 50304);   // 16*260 bf16
    float*  gate1_s = (float*)(pool + 58624);    // 16*132 f32
    float*  gate2_s = (float*)(pool + 67072);    // 16*132 f32
    float*  band_s  = (float*)(pool + 75520);    // 16*132 f32
    float*  mu_s    = (float*)(pool + 83968);    // 48
    float*  rs_s    = (float*)(pool + 84160);    // 48
    char*   qn_c    = pool + 84352;              // 48*128 bf16 swz
    char*   K_c     = pool + 96640;              // 48*128 bf16 swz
    char*   V_c     = pool + 108928;             // 48*128 bf16 swz
    float*  Q_s     = (float*)(pool + 121216);   // 16*132 f32
    float*  sG_s    = (float*)(pool + 129664);   // 16*132 f32
    float*  q1_s    = (float*)(pool + 138112);   // 16*132 f32
    char*   att_c   = pool + 146560;             // 16*128 bf16 swz (C..D)
    char*   hb_c    = pool + 146560;             // 16*512 bf16 swz (F)

    const int tid = threadIdx.x;
    const int l = tid & 63, wv = tid >> 6;
    const int cl = l & 15, kq = l >> 4, ko = kq * 8;
    const int r0 = blockIdx.x * 16;
    const int hb0 = r0 - 16;

    // ---- Phase S: burst-stage all cold global data ----
    for (int i = tid; i < 48 * 32; i += 512) {           // q: 48 rows x 32 float4
        int r = i >> 5, c = (i & 31) << 2;
        int gr = hb0 + r; int grc = gr < 0 ? 0 : (gr >= NA ? NA - 1 : gr);
        *(float4*)&q_s[r * 132 + c] = *(const float4*)&qg[(size_t)grc * DA + c];
    }
    for (int i = tid; i < 48 * 64; i += 512) {           // gb1: 48 x 64 ushort4
        int r = i >> 6, c = (i & 63) << 2;
        int gr = hb0 + r; int grc = gr < 0 ? 0 : (gr >= NA ? NA - 1 : gr);
        *(ushort4*)&gb1_s[r * 260 + c] = *(const ushort4*)&gb1g[(size_t)grc * 256 + c];
    }
    for (int i = tid; i < 16 * 64; i += 512) {           // gb2: 16 x 64 ushort4
        int r = i >> 6, c = (i & 63) << 2;
        *(ushort4*)&gb2_s[r * 260 + c] = *(const ushort4*)&gb2g[(size_t)(r0 + r) * 256 + c];
    }
    for (int i = tid; i < 16 * 32; i += 512) {           // gates: 16 x 32 float4 each
        int r = i >> 5, c = (i & 31) << 2;
        *(float4*)&gate1_s[r * 132 + c] = *(const float4*)&gate1g[(size_t)(r0 + r) * DA + c];
        *(float4*)&gate2_s[r * 132 + c] = *(const float4*)&gate2g[(size_t)(r0 + r) * DA + c];
    }
    for (int i = tid; i < 16 * 33; i += 512) {           // band: 16 x 33 float4
        int r = i >> 5, c = (i & 31) << 2;               // note: 33 f4/row; do 32 + tail
        if ((i & 31) < 32) {
            *(float4*)&band_s[r * 132 + c] = *(const float4*)&bandg[(size_t)(r0 + r) * 132 + c];
        }
    }
    if (tid < 16) {                                      // band tail f4 #32
        *(float4*)&band_s[tid * 132 + 128] = *(const float4*)&bandg[(size_t)(r0 + tid) * 132 + 128];
    }
    __syncthreads();

    // ---- Phase A0: LN1 stats for 48 rows (6 rows per wave) ----
    #pragma unroll
    for (int rr = 0; rr < 6; ++rr) {
        int hr = wv * 6 + rr;
        float2 xv = *(const float2*)&q_s[hr * 132 + 2 * l];
        float sum = xv.x + xv.y, sq = xv.x * xv.x + xv.y * xv.y;
        #pragma unroll
        for (int off = 1; off <= 32; off <<= 1) {
            sum += __shfl_xor(sum, off);
            sq  += __shfl_xor(sq,  off);
        }
        if (l == 0) {
            float m = sum * (1.0f / DA);
            mu_s[hr] = m;
            rs_s[hr] = rsqrtf(sq * (1.0f / DA) - m * m + 1e-5f);
        }
    }
    __syncthreads();

    // ---- Phase A1: LN1 + adaLN modulate -> qn_c (48 rows, elementwise) ----
    for (int i = tid; i < 48 * 16; i += 512) {
        int r = i >> 4, cg = (i & 15) * 8;
        float mu = mu_s[r], rs = rs_s[r];
        ushort4 o0, o1;
        #pragma unroll
        for (int j = 0; j < 8; ++j) {
            float qv = q_s[r * 132 + cg + j];
            float g = bf2f(gb1_s[r * 260 + cg + j]);
            float bb = bf2f(gb1_s[r * 260 + 128 + cg + j]);
            float xn = (qv - mu) * rs * ln_g[cg + j] + ln_b[cg + j];
            ushort v = f2bf((1.f + g) * xn + bb);
            if (j == 0) o0.x = v; else if (j == 1) o0.y = v;
            else if (j == 2) o0.z = v; else if (j == 3) o0.w = v;
            else if (j == 4) o1.x = v; else if (j == 5) o1.y = v;
            else if (j == 6) o1.z = v; else o1.w = v;
        }
        int byte = r * 256 + cg * 2;
        byte ^= (r & 7) << 4;
        *(ushort4*)(qn_c + byte) = o0;
        *(ushort4*)(qn_c + byte + 8) = o1;
    }
    __syncthreads();

    // ---- Phase B: QKVG MFMA. waves 0-5: (tile, K/V); 6: Q; 7: G ----
    {
        int t, isV = 0;
        const ushort* WT;
        if (wv < 6) { t = wv >> 1; isV = wv & 1; WT = isV ? wvT : wkT; }
        else        { t = 1; WT = (wv == 6) ? wqT : wgT; }
        const ushort* Wc = WT + (size_t)cl * DA;
        f32x4 acc[8] = {};
        #pragma unroll
        for (int ks = 0; ks < 4; ++ks) {
            int byteA = (t * 16 + cl) * 256 + (ks * 32 + ko) * 2;
            byteA ^= (cl & 7) << 4;
            bf16x8 a = *(const bf16x8*)(qn_c + byteA);
            #pragma unroll
            for (int nf = 0; nf < 8; ++nf) {
                bf16x8 b = *(const bf16x8*)(Wc + (size_t)nf * 16 * DA + ks * 32 + ko);
                acc[nf] = MFMA(a, b, acc[nf]);
            }
        }
        if (wv < 6) {
            char* dst = isV ? V_c : K_c;
            #pragma unroll
            for (int nf = 0; nf < 8; ++nf)
                #pragma unroll
                for (int r = 0; r < 4; ++r) {
                    int row = t * 16 + kq * 4 + r;
                    int byte = row * 256 + (nf * 16 + cl) * 2;
                    byte ^= (row & 7) << 4;
                    *(ushort*)(dst + byte) = f2bf(acc[nf][r]);
                }
        } else if (wv == 6) {
            #pragma unroll
            for (int nf = 0; nf < 8; ++nf)
                #pragma unroll
                for (int r = 0; r < 4; ++r)
                    Q_s[(kq * 4 + r) * 132 + nf * 16 + cl] = acc[nf][r];
        } else {
            #pragma unroll
            for (int nf = 0; nf < 8; ++nf)
                #pragma unroll
                for (int r = 0; r < 4; ++r)
                    sG_s[(kq * 4 + r) * 132 + nf * 16 + cl] = sigmoidf_(acc[nf][r]);
        }
    }
    __syncthreads();

    // ---- Phase C: banded attention (bf16 K/V in LDS) -> att_c ----
    {
        const int g = tid >> 3, l3 = tid & 7;
        const int rl = g >> 2, h = g & 3;
        const int gr = r0 + rl;
        const float scale = 0.17677669529663687f;   // 1/sqrt(32)
        float4 qr0 = *(const float4*)&Q_s[rl * 132 + h * 32 + l3 * 4];
        const float* brow = band_s + rl * 132 + h * BAND;
        float s[BAND];
        float m = -1e30f;
        #pragma unroll
        for (int jo = 0; jo < BAND; ++jo) {
            int j = gr - WIN + jo;
            float sv = -1e30f;
            if ((unsigned)j < NA) {
                int krow = rl + jo;
                int byte = krow * 256 + (h * 32 + l3 * 4) * 2;
                byte ^= (krow & 7) << 4;
                ushort4 ku = *(const ushort4*)(K_c + byte);
                float d = 0.f;
                d = fmaf(qr0.x, bf2f(ku.x), d);
                d = fmaf(qr0.y, bf2f(ku.y), d);
                d = fmaf(qr0.z, bf2f(ku.z), d);
                d = fmaf(qr0.w, bf2f(ku.w), d);
                d += __shfl_xor(d, 1);
                d += __shfl_xor(d, 2);
                d += __shfl_xor(d, 4);
                sv = fmaf(d, scale, brow[jo]);
            }
            s[jo] = sv;
            m = fmaxf(m, sv);
        }
        float lsum = 0.f;
        #pragma unroll
        for (int jo = 0; jo < BAND; ++jo) {
            float p = __expf(s[jo] - m);
            s[jo] = p;
            lsum += p;
        }
        float inv = 1.0f / lsum;
        float4 o = {0.f, 0.f, 0.f, 0.f};
        #pragma unroll
        for (int jo = 0; jo < BAND; ++jo) {
            int j = gr - WIN + jo;
            if ((unsigned)j < NA) {
                int krow = rl + jo;
                int byte = krow * 256 + (h * 32 + l3 * 4) * 2;
                byte ^= (krow & 7) << 4;
                ushort4 vu = *(const ushort4*)(V_c + byte);
                o.x = fmaf(s[jo], bf2f(vu.x), o.x);
                o.y = fmaf(s[jo], bf2f(vu.y), o.y);
                o.z = fmaf(s[jo], bf2f(vu.z), o.z);
                o.w = fmaf(s[jo], bf2f(vu.w), o.w);
            }
        }
        ushort4 st;
        st.x = f2bf(o.x * inv); st.y = f2bf(o.y * inv);
        st.z = f2bf(o.z * inv); st.w = f2bf(o.w * inv);
        int byte = rl * 256 + h * 64 + l3 * 8;
        byte ^= (rl & 7) << 4;
        *(ushort4*)(att_c + byte) = st;
    }
    __syncthreads();

    // ---- Phase D: wo MFMA + gated residual -> q1_s ----
    {
        const int n0 = wv * 16;
        const ushort* Wc = woT + (size_t)(n0 + cl) * DA;
        f32x4 acc = {0.f, 0.f, 0.f, 0.f};
        #pragma unroll
        for (int ks = 0; ks < 4; ++ks) {
            int byteA = cl * 256 + (ks * 32 + ko) * 2;
            byteA ^= (cl & 7) << 4;
            bf16x8 a = *(const bf16x8*)(att_c + byteA);
            bf16x8 b = *(const bf16x8*)(Wc + ks * 32 + ko);
            acc = MFMA(a, b, acc);
        }
        #pragma unroll
        for (int r = 0; r < 4; ++r) {
            int row = kq * 4 + r, col = n0 + cl;
            float qv = q_s[(16 + row) * 132 + col];
            float sg = sG_s[row * 132 + col];
            float g1v = gate1_s[row * 132 + col];
            q1_s[row * 132 + col] = (qv + sg * acc[r]) * (1.f + g1v);
        }
    }
    __syncthreads();

    // ---- Phase E: LN2 + gb2 modulate (in-reg, lane cl owns row cl) ----
    bf16x8 afr[4];
    {
        const int row = cl;
        float qv2[4][8];
        float sum = 0.f, sq = 0.f;
        #pragma unroll
        for (int ks = 0; ks < 4; ++ks) {
            float4 v0 = *(const float4*)&q1_s[row * 132 + ks * 32 + ko];
            float4 v1 = *(const float4*)&q1_s[row * 132 + ks * 32 + ko + 4];
            qv2[ks][0] = v0.x; qv2[ks][1] = v0.y; qv2[ks][2] = v0.z; qv2[ks][3] = v0.w;
            qv2[ks][4] = v1.x; qv2[ks][5] = v1.y; qv2[ks][6] = v1.z; qv2[ks][7] = v1.w;
            sum += v0.x + v0.y + v0.z + v0.w + v1.x + v1.y + v1.z + v1.w;
            sq += v0.x * v0.x + v0.y * v0.y + v0.z * v0.z + v0.w * v0.w
                + v1.x * v1.x + v1.y * v1.y + v1.z * v1.z + v1.w * v1.w;
        }
        sum += __shfl_xor(sum, 16); sq += __shfl_xor(sq, 16);
        sum += __shfl_xor(sum, 32); sq += __shfl_xor(sq, 32);
        float mean = sum * (1.0f / DA);
        float rs = rsqrtf(sq * (1.0f / DA) - mean * mean + 1e-5f);
        #pragma unroll
        for (int ks = 0; ks < 4; ++ks) {
            int k = ks * 32 + ko;
            ushort4 g0 = *(const ushort4*)&gb2_s[row * 260 + k];
            ushort4 g1u = *(const ushort4*)&gb2_s[row * 260 + k + 4];
            ushort4 b0 = *(const ushort4*)&gb2_s[row * 260 + 128 + k];
            ushort4 b1u = *(const ushort4*)&gb2_s[row * 260 + 128 + k + 4];
            float gg[8] = {bf2f(g0.x), bf2f(g0.y), bf2f(g0.z), bf2f(g0.w),
                           bf2f(g1u.x), bf2f(g1u.y), bf2f(g1u.z), bf2f(g1u.w)};
            float bb[8] = {bf2f(b0.x), bf2f(b0.y), bf2f(b0.z), bf2f(b0.w),
                           bf2f(b1u.x), bf2f(b1u.y), bf2f(b1u.z), bf2f(b1u.w)};
            #pragma unroll
            for (int j = 0; j < 8; ++j) {
                float xn = (qv2[ks][j] - mean) * rs;
                afr[ks][j] = (short)f2bf((1.f + gg[j]) * xn + bb[j]);
            }
        }
    }

    // ---- Phase F: sw1/sw3 -> hb_c (aliases att); sw2 -> out ----
    {
        const int c0 = wv * 64;
        const ushort* W1 = s1T + (size_t)(c0 + cl) * DA;
        const ushort* W3 = s3T + (size_t)(c0 + cl) * DA;
        f32x4 acc1[4] = {}, acc3[4] = {};
        #pragma unroll
        for (int ks = 0; ks < 4; ++ks) {
            #pragma unroll
            for (int nf = 0; nf < 4; ++nf) {
                bf16x8 b1 = *(const bf16x8*)(W1 + (size_t)nf * 16 * DA + ks * 32 + ko);
                acc1[nf] = MFMA(afr[ks], b1, acc1[nf]);
                bf16x8 b3 = *(const bf16x8*)(W3 + (size_t)nf * 16 * DA + ks * 32 + ko);
                acc3[nf] = MFMA(afr[ks], b3, acc3[nf]);
            }
        }
        #pragma unroll
        for (int nf = 0; nf < 4; ++nf) {
            #pragma unroll
            for (int r = 0; r < 4; ++r) {
                float x1 = acc1[nf][r], x3 = acc3[nf][r];
                float h = x1 * sigmoidf_(x1) * x3;
                int rr = kq * 4 + r;
                int col = c0 + nf * 16 + cl;
                int byte = rr * 1024 + col * 2;
                byte ^= (rr & 7) << 4;
                *(ushort*)(hb_c + byte) = f2bf(h);
            }
        }
    }
    __syncthreads();
    {
        const int n0 = wv * 16;
        const ushort* W2 = s2T + (size_t)(n0 + cl) * DF;
        f32x4 acc = {0.f, 0.f, 0.f, 0.f};
        #pragma unroll
        for (int ks = 0; ks < 16; ++ks) {
            int byteA = cl * 1024 + (ks * 32 + ko) * 2;
            byteA ^= (cl & 7) << 4;
            bf16x8 a = *(const bf16x8*)(hb_c + byteA);
            bf16x8 b = *(const bf16x8*)(W2 + ks * 32 + ko);
            acc = MFMA(a, b, acc);
        }
        #pragma unroll
        for (int r = 0; r < 4; ++r) {
            int row = kq * 4 + r, col = n0 + cl;
            size_t rc = (size_t)(r0 + row) * DA + col;
            out[rc] = q1_s[row * 132 + col] + gate2_s[row * 132 + col] * acc[r];
        }
    }
}

// ---------------------------------------------------------------------------
extern "C" void kernel_launch(void* const* d_in, const int* in_sizes, int n_in,
                              void* d_out, int out_size, void* d_ws, size_t ws_size,
                              hipStream_t stream)
{
    const float* q      = (const float*)d_in[0];
    const float* c_atom = (const float*)d_in[1];
    const float* h_cond = (const float*)d_in[2];
    const float* p_lm   = (const float*)d_in[3];
    const float* t_emb  = (const float*)d_in[4];
    const float* cond_w = (const float*)d_in[5];
    const float* cond_b = (const float*)d_in[6];
    const float* ad1w   = (const float*)d_in[7];
    const float* ad1b   = (const float*)d_in[8];
    const float* ad2w   = (const float*)d_in[9];
    const float* ad2b   = (const float*)d_in[10];
    const float* ln_g   = (const float*)d_in[11];
    const float* ln_b   = (const float*)d_in[12];
    const float* wq     = (const float*)d_in[13];
    const float* wk     = (const float*)d_in[14];
    const float* wv     = (const float*)d_in[15];
    const float* wg     = (const float*)d_in[16];
    const float* wo     = (const float*)d_in[17];
    const float* pair_w = (const float*)d_in[18];
    const float* pair_b = (const float*)d_in[19];
    const float* g1w    = (const float*)d_in[20];
    const float* g1b    = (const float*)d_in[21];
    const float* g2w    = (const float*)d_in[22];
    const float* g2b    = (const float*)d_in[23];
    const float* sw1    = (const float*)d_in[24];
    const float* sw3    = (const float*)d_in[25];
    const float* sw2    = (const float*)d_in[26];
    const int*   p_idx  = (const int*)d_in[27];
    const int*   tok    = (const int*)d_in[28];
    float* out = (float*)d_out;

    size_t off = 0;
    char* base = (char*)d_ws;
    auto alloc = [&](size_t bytes) -> void* {
        void* p = base + off;
        off += (bytes + 255) & ~(size_t)255;
        return p;
    };
    ushort* cwT   = (ushort*)alloc((size_t)DM * DA * 2);
    ushort* a1T   = (ushort*)alloc((size_t)256 * 128 * 2);
    ushort* a2T   = (ushort*)alloc((size_t)256 * 128 * 2);
    ushort* wqT   = (ushort*)alloc((size_t)128 * 128 * 2);
    ushort* wkT   = (ushort*)alloc((size_t)128 * 128 * 2);
    ushort* wvT   = (ushort*)alloc((size_t)128 * 128 * 2);
    ushort* wgT   = (ushort*)alloc((size_t)128 * 128 * 2);
    ushort* woT   = (ushort*)alloc((size_t)128 * 128 * 2);
    ushort* g1T   = (ushort*)alloc((size_t)128 * 128 * 2);
    ushort* g2T   = (ushort*)alloc((size_t)128 * 128 * 2);
    ushort* s1T   = (ushort*)alloc((size_t)512 * 128 * 2);
    ushort* s3T   = (ushort*)alloc((size_t)512 * 128 * 2);
    ushort* s2T   = (ushort*)alloc((size_t)128 * 512 * 2);
    ushort* gb1   = (ushort*)alloc((size_t)NA * 256 * 2);
    ushort* gb2   = (ushort*)alloc((size_t)NA * 256 * 2);
    float*  gate1 = (float*)alloc((size_t)NA * DA * 4);
    float*  gate2 = (float*)alloc((size_t)NA * DA * 4);
    float*  band  = (float*)alloc((size_t)NA * HH * BAND * 4);

    k_prep<<<dim3(64, 14), 256, 0, stream>>>(
        cond_w, ad1w, ad2w, wq, wk, wv, wg, wo, g1w, g2w, sw1, sw3, sw2,
        cwT, a1T, a2T, wqT, wkT, wvT, wgT, woT, g1T, g2T, s1T, s3T, s2T, band);
    k_condmod<<<384, 256, 0, stream>>>(
        h_cond, tok, cwT, t_emb, cond_b, c_atom,
        a1T, a2T, g1T, g2T, ad1b, ad2b, g1b, g2b,
        p_lm, pair_w, pair_b, p_idx, band,
        gb1, gb2, gate1, gate2);
    k_mega<<<256, 512, 0, stream>>>(
        q, gb1, gb2, gate1, gate2, ln_g, ln_b, band,
        wqT, wkT, wvT, wgT, woT, s1T, s3T, s2T, out);
    (void)in_sizes; (void)n_in; (void)out_size; (void)ws_size;
}